// Round 5
// baseline (1085.500 us; speedup 1.0000x reference)
//
#include <hip/hip_runtime.h>

#define DEVINL __device__ __forceinline__

typedef unsigned int  uint32;
typedef unsigned short u16;

typedef short bf16x8  __attribute__((ext_vector_type(8)));
typedef float f32x16  __attribute__((ext_vector_type(16)));
typedef float fx2     __attribute__((ext_vector_type(2)));

union U4H { uint4 u; bf16x8 h; };

// ---------------- path tables (15 paths, enumeration order of reference) ----
// idx: 0:(0,0,0,0,F) 1:(0,1,1,0,F) 2:(0,2,2,0,F) 3:(1,0,1,0,F) 4:(1,1,2,0,F)
//      5:(1,1,0,1,F) 6:(1,1,1,0,T) 7:(1,2,1,1,F) 8:(1,2,2,0,T) 9:(2,0,2,0,F)
//     10:(2,1,1,1,F) 11:(2,1,2,0,T) 12:(2,2,2,1,F) 13:(2,2,0,2,F) 14:(2,2,1,1,T)
constexpr int PL1c[15] = {0,0,0,1,1,1,1,1,1,2,2,2,2,2,2};
constexpr int PL2c[15] = {0,1,2,0,1,1,1,2,2,0,1,1,2,2,2};
constexpr int PLOc[15] = {0,1,2,1,2,0,1,1,2,2,1,2,2,0,1};
constexpr int PTc [15] = {1,1,1,1,1,3,2,3,2,1,3,2,3,9,6};
constexpr int PW3c[3]  = {1,3,9};
constexpr int LOFFc[3] = {0,32,128};

// groups g = (s_out = g&1, Lout = g>>1); combos (path, s1, s2)
constexpr int GCNT[6] = {6,6,12,12,12,12};
constexpr int GNT [6] = {1,1,3,3,9,9};
__device__ const int g_combo[6][12][3] = {
  {{0,0,0},{0,1,1},{5,0,0},{5,1,1},{13,0,0},{13,1,1},
   {0,0,0},{0,0,0},{0,0,0},{0,0,0},{0,0,0},{0,0,0}},
  {{0,0,1},{0,1,0},{5,0,1},{5,1,0},{13,0,1},{13,1,0},
   {0,0,0},{0,0,0},{0,0,0},{0,0,0},{0,0,0},{0,0,0}},
  {{1,0,0},{1,1,1},{3,0,0},{3,1,1},{7,0,0},{7,1,1},{10,0,0},{10,1,1},
   {6,0,1},{6,1,0},{14,0,1},{14,1,0}},
  {{1,0,1},{1,1,0},{3,0,1},{3,1,0},{7,0,1},{7,1,0},{10,0,1},{10,1,0},
   {6,0,0},{6,1,1},{14,0,0},{14,1,1}},
  {{2,0,0},{2,1,1},{4,0,0},{4,1,1},{9,0,0},{9,1,1},{12,0,0},{12,1,1},
   {8,0,1},{8,1,0},{11,0,1},{11,1,0}},
  {{2,0,1},{2,1,0},{4,0,1},{4,1,0},{9,0,1},{9,1,0},{12,0,1},{12,1,0},
   {8,0,0},{8,1,1},{11,0,0},{11,1,1}},
};

struct Terms { int iA[9]; int jB[9]; int sg[9]; };

DEVINL Terms make_terms(int path, int mo) {
  Terms t{};
  switch (path) {
    case 0:  t.iA[0]=0;  t.jB[0]=0;  t.sg[0]=1; break;
    case 1:  t.iA[0]=0;  t.jB[0]=mo; t.sg[0]=1; break;
    case 2:  t.iA[0]=0;  t.jB[0]=mo; t.sg[0]=1; break;
    case 3:  t.iA[0]=mo; t.jB[0]=0;  t.sg[0]=1; break;
    case 4:  t.iA[0]=mo/3; t.jB[0]=mo%3; t.sg[0]=1; break;
    case 5:  for (int v=0;v<3;++v){t.iA[v]=v; t.jB[v]=v; t.sg[v]=1;} break;
    case 6:  {int p=mo,u1=(p+1)%3,u2=(p+2)%3;
              t.iA[0]=u1; t.jB[0]=u2; t.sg[0]= 1;
              t.iA[1]=u2; t.jB[1]=u1; t.sg[1]=-1;} break;
    case 7:  {int x=mo; for(int u=0;u<3;++u){t.iA[u]=u; t.jB[u]=3*x+u; t.sg[u]=1;}} break;
    case 8:  {int x=mo/3,p=mo%3,u1=(p+1)%3,u2=(p+2)%3;
              t.iA[0]=u1; t.jB[0]=3*x+u2; t.sg[0]= 1;
              t.iA[1]=u2; t.jB[1]=3*x+u1; t.sg[1]=-1;} break;
    case 9:  t.iA[0]=mo; t.jB[0]=0; t.sg[0]=1; break;
    case 10: {int u=mo; for(int v=0;v<3;++v){t.iA[v]=3*u+v; t.jB[v]=v; t.sg[v]=1;}} break;
    case 11: {int u=mo/3,p=mo%3,v1=(p+1)%3,v2=(p+2)%3;
              t.iA[0]=3*u+v1; t.jB[0]=v2; t.sg[0]= 1;
              t.iA[1]=3*u+v2; t.jB[1]=v1; t.sg[1]=-1;} break;
    case 12: {int u=mo/3,x=mo%3; for(int v=0;v<3;++v){t.iA[v]=3*u+v; t.jB[v]=3*x+v; t.sg[v]=1;}} break;
    case 13: for (int w=0;w<9;++w){t.iA[w]=w; t.jB[w]=w; t.sg[w]=1;} break;
    case 14: {int p=mo,u1=(p+1)%3,u2=(p+2)%3;
              for(int v=0;v<3;++v){
                t.iA[2*v]  =3*u1+v; t.jB[2*v]  =3*u2+v; t.sg[2*v]  = 1;
                t.iA[2*v+1]=3*u2+v; t.jB[2*v+1]=3*u1+v; t.sg[2*v+1]=-1;}} break;
  }
  return t;
}

DEVINL u16 f2bf(float f) {            // RNE float->bf16
  uint32 u = __float_as_uint(f);
  u += 0x7fffu + ((u >> 16) & 1u);
  return (u16)(u >> 16);
}
DEVINL float bf2f(u16 h) { return __uint_as_float(((uint32)h) << 16); }

DEVINL void unpack8(uint4 r, fx2 out[4]) {   // sign applied on A scalar instead
  uint32 c[4] = {r.x, r.y, r.z, r.w};
#pragma unroll
  for (int q = 0; q < 4; ++q) {
    out[q].x = __uint_as_float(c[q] << 16);
    out[q].y = __uint_as_float(c[q] & 0xffff0000u);
  }
}

DEVINL bf16x8 packA(const fx2 p[4]) { // pack 8 f32 -> 8 bf16 (truncate)
  U4H r;
  r.u.x = __builtin_amdgcn_perm(__float_as_uint(p[0].y), __float_as_uint(p[0].x), 0x07060302u);
  r.u.y = __builtin_amdgcn_perm(__float_as_uint(p[1].y), __float_as_uint(p[1].x), 0x07060302u);
  r.u.z = __builtin_amdgcn_perm(__float_as_uint(p[2].y), __float_as_uint(p[2].x), 0x07060302u);
  r.u.w = __builtin_amdgcn_perm(__float_as_uint(p[3].y), __float_as_uint(p[3].x), 0x07060302u);
  return r.h;
}

DEVINL f32x16 mfma32(bf16x8 a, uint4 w, f32x16 c) {
  U4H x; x.u = w;
  return __builtin_amdgcn_mfma_f32_32x32x16_bf16(a, x.h, c, 0, 0, 0);
}

// x1l row stride: 834 u16 = 417 dwords == 1 (mod 32) -> the 32-row fixed-column
// read pattern hits all 32 banks (conflict-free).
#define X1STRIDE 834

// ---------------- per-combo worker -----------------------------------------
// R10: 16-wave block. Wave split: bh = wv&1 (16-wide b half),
// a0 = (wv>>1)*4 (4 'a' channels per wave, 8 a-groups). wf[4] resident.
// Rationale: three rounds of evidence (R6/R7/R9) show a second 512-thread
// workgroup never co-resides on a CU regardless of VGPR (128->88) and LDS
// (66->57.8KB). A single 1024-thread workgroup forces 16 waves onto one CU
// (workgroup residency is atomic) -> 4 waves/SIMD without dispatcher help.
template<int PATH, int MO>
DEVINL void run_combo(int s1, int s2, int n0,
                      const u16* __restrict__ x2t, const u16* x1l,
                      const uint4* __restrict__ wgl,
                      f32x16& acc, int lane, int wv)
{
  constexpr int L1v = PL1c[PATH];
  constexpr int L2v = PL2c[PATH];
  constexpr int T   = PTc[PATH];
  constexpr int P1v = PW3c[L1v];
  constexpr int NCH = (T + 2) / 3;
  const int bh   = wv & 1;
  const int a0   = (wv >> 1) * 4;
  const int nloc = lane & 31;
  const int oct  = lane >> 5;
  const u16* bb = x2t + (size_t)(n0 + nloc) * 832 + s2 * 416 + LOFFc[L2v]
                + bh * 16 + oct * 8;
  const u16* ab = x1l + nloc * X1STRIDE + s1 * 416 + LOFFc[L1v];
  const uint4* wbase = wgl + ((a0 * 2 + bh) << 6) + lane;
  uint4 wf[4];                           // resident for the whole combo
#pragma unroll
  for (int ia = 0; ia < 4; ++ia)
    wf[ia] = wbase[ia * 128];            // global_load_dwordx4, L2 hit
  const Terms tm = make_terms(PATH, MO); // PATH, MO compile-time -> folded
#pragma unroll
  for (int tc = 0; tc < NCH; ++tc) {
    const int tlo = tc * 3;
    const int tn  = (T - tlo < 3) ? (T - tlo) : 3;
    fx2 b2[3][4];
#pragma unroll
    for (int u = 0; u < 3; ++u)
      if (u < tn) {
        uint4 rv = *(const uint4*)(bb + tm.jB[tlo + u] * 32);
        unpack8(rv, b2[u]);
      }
#pragma unroll
    for (int ia = 0; ia < 4; ++ia) {
      fx2 p[4];
#pragma unroll
      for (int u = 0; u < 3; ++u) {
        if (u < tn) {
          float av = bf2f(ab[(a0 + ia) * P1v + tm.iA[tlo + u]]);
          if (tm.sg[tlo + u] < 0) av = -av;
          fx2 a2; a2.x = av; a2.y = av;
          if (u == 0) {
#pragma unroll
            for (int q = 0; q < 4; ++q) p[q] = a2 * b2[0][q];
          } else {
#pragma unroll
            for (int q = 0; q < 4; ++q)
              p[q] = __builtin_elementwise_fma(a2, b2[u][q], p[q]);
          }
        }
      }
      acc = mfma32(packA(p), wf[ia], acc);
    }
  }
}

// one accumulator chunk (single t = MOB) over ALL combos of group G, then
// LDS-combine across 16 waves and store this chunk's output column.
// Store: coalesced full-line writes into column-major scratch sc[col][n]
// (128B contiguous per 32 lanes -> no partial-line RMW). k_tr -> out.
// red swizzle (col<<5)+((row+col)&31): conflict-free for both the atomic
// flush (banks = (row+col)&31, distinct per lane) and the store read.
template<int G, int MOB>
DEVINL void process_chunk(int n0, const u16* __restrict__ x2t, const u16* x1l,
                          const uint4* __restrict__ Wb, float* red,
                          float* __restrict__ out, float* __restrict__ sc,
                          int use_sc, int tid, int lane, int wv)
{
  constexpr int lout  = G >> 1;
  constexpr int s_out = G & 1;
  constexpr int NTF   = GNT[G];
  f32x16 acc;
#pragma unroll
  for (int e = 0; e < 16; ++e) acc[e] = 0.f;

#pragma unroll 1
  for (int ci = 0; ci < GCNT[G]; ++ci) {
    const int path = g_combo[G][ci][0];
    const int s1   = g_combo[G][ci][1];
    const int s2   = g_combo[G][ci][2];
    const int pc   = path * 4 + s1 * 2 + s2;
    const uint4* wgl = Wb + ((size_t)pc << 12);
#define RCASE(P) case P: if constexpr (PLOc[P] == lout) \
      run_combo<P, MOB>(s1, s2, n0, x2t, x1l, wgl, acc, lane, wv); break;
    switch (path) {
      RCASE(0) RCASE(1) RCASE(2) RCASE(3) RCASE(4) RCASE(5) RCASE(6) RCASE(7)
      RCASE(8) RCASE(9) RCASE(10) RCASE(11) RCASE(12) RCASE(13) RCASE(14)
    }
#undef RCASE
    __builtin_amdgcn_sched_barrier(0);   // no cross-combo code motion
  }
  const int col = lane & 31, oct = lane >> 5;
  constexpr int obase = s_out * 416 + LOFFc[lout];
  __syncthreads();                       // red zeroed & prior readers done
#pragma unroll
  for (int r = 0; r < 16; ++r) {
    int row = (r & 3) + 8 * (r >> 2) + 4 * oct;   // m74/m101 C/D layout
    atomicAdd(&red[(col << 5) + ((row + col) & 31)], acc[r]);
  }
  __syncthreads();                       // all atomics done
  for (int o = tid; o < 1024; o += 1024) {
    int row = o & 31;                    // row fastest -> coalesced sc write
    int Z   = o >> 5;
    int idx = (Z << 5) + ((row + Z) & 31);
    float v = red[idx];
    red[idx] = 0.f;                      // restore invariant for next round
    int colx = obase + Z * NTF + MOB;
    if (use_sc) sc[(size_t)colx * 8192 + n0 + row] = v;
    else        out[(size_t)(n0 + row) * 832 + colx] = v;
  }
}

template<int G>
DEVINL void process_group(int n0, const u16* __restrict__ x2t, const u16* x1l,
                          const uint4* __restrict__ Wb, float* red,
                          float* __restrict__ out, float* __restrict__ sc,
                          int use_sc, int tid, int lane, int wv)
{
  process_chunk<G, 0>(n0, x2t, x1l, Wb, red, out, sc, use_sc, tid, lane, wv);
  if constexpr (GNT[G] >= 3) {
    process_chunk<G, 1>(n0, x2t, x1l, Wb, red, out, sc, use_sc, tid, lane, wv);
    process_chunk<G, 2>(n0, x2t, x1l, Wb, red, out, sc, use_sc, tid, lane, wv);
  }
  if constexpr (GNT[G] == 9) {
    process_chunk<G, 3>(n0, x2t, x1l, Wb, red, out, sc, use_sc, tid, lane, wv);
    process_chunk<G, 4>(n0, x2t, x1l, Wb, red, out, sc, use_sc, tid, lane, wv);
    process_chunk<G, 5>(n0, x2t, x1l, Wb, red, out, sc, use_sc, tid, lane, wv);
    process_chunk<G, 6>(n0, x2t, x1l, Wb, red, out, sc, use_sc, tid, lane, wv);
    process_chunk<G, 7>(n0, x2t, x1l, Wb, red, out, sc, use_sc, tid, lane, wv);
    process_chunk<G, 8>(n0, x2t, x1l, Wb, red, out, sc, use_sc, tid, lane, wv);
  }
}

// ---------------- main kernel ----------------------------------------------
// R10: ONE 1024-thread workgroup per slab (grid 256). 16 waves co-resident
// by construction (workgroup residency is atomic) = 4 waves/SIMD = target
// 50% occupancy. LDS 57,472 B single copy. __launch_bounds__(1024,4):
// 4 waves/EU floor -> regalloc capped at 128 VGPR (required for a 16-wave
// workgroup to be launchable at all; R9 measured 88 with the fatter wf[8]).
// Per-wave MFMA work: 1280 (halved vs 8-wave layout); 26 flush rounds.
__global__ __launch_bounds__(1024, 4)
void k_main(const float* __restrict__ x1, const u16* __restrict__ x2t,
            const uint4* __restrict__ Wb, float* __restrict__ out,
            float* __restrict__ sc, int use_sc)
{
  __shared__ u16   x1l[32 * X1STRIDE]; // 53,376 B (stride 834: conflict-free)
  __shared__ float red[1024];          // 4,096 B cross-wave accumulator
  const int tid  = threadIdx.x;
  const int lane = tid & 63, wv = tid >> 6;
  const int n0   = blockIdx.x * 32;

  { // stage x1 rows -> bf16 LDS (once): 32 threads per row, 26 cols each
    int rr = tid >> 5, c0 = tid & 31;
    const float* src = x1 + (size_t)(n0 + rr) * 832;
#pragma unroll 2
    for (int jj = 0; jj < 26; ++jj) {
      int colx = c0 + jj * 32;
      x1l[rr * X1STRIDE + colx] = f2bf(src[colx]);
    }
  }
  for (int o = tid; o < 1024; o += 1024) red[o] = 0.f;  // flush invariant
  __syncthreads();                       // x1l staged + red zeroed

  process_group<0>(n0, x2t, x1l, Wb, red, out, sc, use_sc, tid, lane, wv);
  process_group<1>(n0, x2t, x1l, Wb, red, out, sc, use_sc, tid, lane, wv);
  process_group<2>(n0, x2t, x1l, Wb, red, out, sc, use_sc, tid, lane, wv);
  process_group<3>(n0, x2t, x1l, Wb, red, out, sc, use_sc, tid, lane, wv);
  process_group<4>(n0, x2t, x1l, Wb, red, out, sc, use_sc, tid, lane, wv);
  process_group<5>(n0, x2t, x1l, Wb, red, out, sc, use_sc, tid, lane, wv);
}

// ---------------- transpose kernel: sc[col][n] -> out[n][col] ---------------
// 32 cols x 64 rows per block; both global phases fully coalesced/full-line.
__global__ __launch_bounds__(256)
void k_tr(const float* __restrict__ sc, float* __restrict__ out)
{
  __shared__ float tile[32][65];
  const int tid = threadIdx.x;
  const int cb  = blockIdx.x % 26;
  const int nbk = blockIdx.x / 26;
  if (cb >= 26 || nbk >= 128) return;    // defensive (grid == 26*128 exactly)
  const int c0  = cb * 32;
  const int nb  = nbk * 64;
#pragma unroll
  for (int it = 0; it < 8; ++it) {
    int idx = it * 256 + tid;
    int c = idx >> 6, n = idx & 63;      // n fastest -> coalesced read
    tile[c][n] = sc[(size_t)(c0 + c) * 8192 + nb + n];
  }
  __syncthreads();
#pragma unroll
  for (int it = 0; it < 8; ++it) {
    int idx = it * 256 + tid;
    int c = idx & 31, n = idx >> 5;      // c fastest -> coalesced write
    out[(size_t)(nb + n) * 832 + c0 + c] = tile[c][n];
  }
}

// ---------------- pre-kernels ----------------------------------------------
// W -> bf16, swizzled into exact B-fragment lane order:
//   Wb[pc][a][bh][l][j] = bf16( w[pc*32768 + Z*1024 + a*32 + b] ),
//   Z = l&31, b = bh*16 + ((l>>5)&1)*8 + j
__global__ void k_convw(const float* __restrict__ w, u16* __restrict__ Wb) {
  int o  = blockIdx.x * 1024 + threadIdx.x;      // 1,966,080 total
  int j  = o & 7;
  int l  = (o >> 3) & 63;
  int bh = (o >> 9) & 1;
  int a  = (o >> 10) & 31;
  int pc = o >> 15;
  int Z  = l & 31;
  int b  = bh * 16 + ((l >> 5) & 1) * 8 + j;
  float f = w[((size_t)pc << 15) + (size_t)Z * 1024 + a * 32 + b];
  Wb[o] = f2bf(f);
}

// x2 -> bf16, transposed within each (s,L) block to [j][b] so 8 consecutive
// b-channels are one 16B load: x2t[n*832 + s*416 + Loff + j*32 + b]
__global__ void k_convx2(const float* __restrict__ x2, u16* __restrict__ x2t) {
  int o = blockIdx.x * 1024 + threadIdx.x;       // 6,815,744 total
  int n = o / 832; int r = o - n * 832;
  int s = (r >= 416); int r2 = r - s * 416;
  int L = (r2 >= 32) + (r2 >= 128);
  int off = (L == 0) ? 0 : ((L == 1) ? 32 : 128);
  int c = r2 - off;
  int j = c >> 5, b = c & 31;
  int p3 = (L == 0) ? 1 : ((L == 1) ? 3 : 9);
  float f = x2[(size_t)n * 832 + s * 416 + off + b * p3 + j];
  x2t[o] = f2bf(f);
}

// ---------------- launch ----------------------------------------------------
extern "C" void kernel_launch(void* const* d_in, const int* in_sizes, int n_in,
                              void* d_out, int out_size, void* d_ws, size_t ws_size,
                              hipStream_t stream) {
  const float* x1 = (const float*)d_in[0];
  const float* x2 = (const float*)d_in[1];
  const float* w  = (const float*)d_in[2];
  float* out = (float*)d_out;
  // ws layout: [0,4MB) swizzled bf16 W ; [4MB,~17.6MB) bf16 x2t ;
  //            [20MB, 20MB+27.3MB) f32 scratch sc[832][8192]
  u16*   Wb  = (u16*)d_ws;
  u16*   x2t = (u16*)((char*)d_ws + (4u << 20));
  float* sc  = (float*)((char*)d_ws + (20u << 20));
  const size_t sc_need = (20u << 20) + (size_t)832 * 8192 * 4;
  const int use_sc = (ws_size >= sc_need) ? 1 : 0;
  (void)in_sizes; (void)n_in; (void)out_size;

  k_convw <<<1920, 1024, 0, stream>>>(w, Wb);    // 1920*1024 = 1,966,080
  k_convx2<<<6656, 1024, 0, stream>>>(x2, x2t);  // 6656*1024 = 6,815,744
  k_main  <<<256, 1024, 0, stream>>>(x1, x2t, (const uint4*)Wb, out, sc, use_sc);
  if (use_sc) k_tr<<<26 * 128, 256, 0, stream>>>(sc, out);
}

// Round 7
// 781.900 us; speedup vs baseline: 1.3883x; 1.3883x over previous
//
#include <hip/hip_runtime.h>

#define DEVINL __device__ __forceinline__

typedef unsigned int  uint32;
typedef unsigned short u16;

typedef short bf16x8  __attribute__((ext_vector_type(8)));
typedef float f32x16  __attribute__((ext_vector_type(16)));
typedef float fx2     __attribute__((ext_vector_type(2)));

union U4H { uint4 u; bf16x8 h; };

// ---------------- path tables (15 paths, enumeration order of reference) ----
// idx: 0:(0,0,0,0,F) 1:(0,1,1,0,F) 2:(0,2,2,0,F) 3:(1,0,1,0,F) 4:(1,1,2,0,F)
//      5:(1,1,0,1,F) 6:(1,1,1,0,T) 7:(1,2,1,1,F) 8:(1,2,2,0,T) 9:(2,0,2,0,F)
//     10:(2,1,1,1,F) 11:(2,1,2,0,T) 12:(2,2,2,1,F) 13:(2,2,0,2,F) 14:(2,2,1,1,T)
constexpr int PL1c[15] = {0,0,0,1,1,1,1,1,1,2,2,2,2,2,2};
constexpr int PL2c[15] = {0,1,2,0,1,1,1,2,2,0,1,1,2,2,2};
constexpr int PLOc[15] = {0,1,2,1,2,0,1,1,2,2,1,2,2,0,1};
constexpr int PTc [15] = {1,1,1,1,1,3,2,3,2,1,3,2,3,9,6};
constexpr int PW3c[3]  = {1,3,9};
constexpr int LOFFc[3] = {0,32,128};

// groups g = (s_out = g&1, Lout = g>>1); combos (path, s1, s2)
constexpr int GCNT[6] = {6,6,12,12,12,12};
constexpr int GNT [6] = {1,1,3,3,9,9};
__device__ const int g_combo[6][12][3] = {
  {{0,0,0},{0,1,1},{5,0,0},{5,1,1},{13,0,0},{13,1,1},
   {0,0,0},{0,0,0},{0,0,0},{0,0,0},{0,0,0},{0,0,0}},
  {{0,0,1},{0,1,0},{5,0,1},{5,1,0},{13,0,1},{13,1,0},
   {0,0,0},{0,0,0},{0,0,0},{0,0,0},{0,0,0},{0,0,0}},
  {{1,0,0},{1,1,1},{3,0,0},{3,1,1},{7,0,0},{7,1,1},{10,0,0},{10,1,1},
   {6,0,1},{6,1,0},{14,0,1},{14,1,0}},
  {{1,0,1},{1,1,0},{3,0,1},{3,1,0},{7,0,1},{7,1,0},{10,0,1},{10,1,0},
   {6,0,0},{6,1,1},{14,0,0},{14,1,1}},
  {{2,0,0},{2,1,1},{4,0,0},{4,1,1},{9,0,0},{9,1,1},{12,0,0},{12,1,1},
   {8,0,1},{8,1,0},{11,0,1},{11,1,0}},
  {{2,0,1},{2,1,0},{4,0,1},{4,1,0},{9,0,1},{9,1,0},{12,0,1},{12,1,0},
   {8,0,0},{8,1,1},{11,0,0},{11,1,1}},
};

struct Terms { int iA[9]; int jB[9]; int sg[9]; };

DEVINL Terms make_terms(int path, int mo) {
  Terms t{};
  switch (path) {
    case 0:  t.iA[0]=0;  t.jB[0]=0;  t.sg[0]=1; break;
    case 1:  t.iA[0]=0;  t.jB[0]=mo; t.sg[0]=1; break;
    case 2:  t.iA[0]=0;  t.jB[0]=mo; t.sg[0]=1; break;
    case 3:  t.iA[0]=mo; t.jB[0]=0;  t.sg[0]=1; break;
    case 4:  t.iA[0]=mo/3; t.jB[0]=mo%3; t.sg[0]=1; break;
    case 5:  for (int v=0;v<3;++v){t.iA[v]=v; t.jB[v]=v; t.sg[v]=1;} break;
    case 6:  {int p=mo,u1=(p+1)%3,u2=(p+2)%3;
              t.iA[0]=u1; t.jB[0]=u2; t.sg[0]= 1;
              t.iA[1]=u2; t.jB[1]=u1; t.sg[1]=-1;} break;
    case 7:  {int x=mo; for(int u=0;u<3;++u){t.iA[u]=u; t.jB[u]=3*x+u; t.sg[u]=1;}} break;
    case 8:  {int x=mo/3,p=mo%3,u1=(p+1)%3,u2=(p+2)%3;
              t.iA[0]=u1; t.jB[0]=3*x+u2; t.sg[0]= 1;
              t.iA[1]=u2; t.jB[1]=3*x+u1; t.sg[1]=-1;} break;
    case 9:  t.iA[0]=mo; t.jB[0]=0; t.sg[0]=1; break;
    case 10: {int u=mo; for(int v=0;v<3;++v){t.iA[v]=3*u+v; t.jB[v]=v; t.sg[v]=1;}} break;
    case 11: {int u=mo/3,p=mo%3,v1=(p+1)%3,v2=(p+2)%3;
              t.iA[0]=3*u+v1; t.jB[0]=v2; t.sg[0]= 1;
              t.iA[1]=3*u+v2; t.jB[1]=v1; t.sg[1]=-1;} break;
    case 12: {int u=mo/3,x=mo%3; for(int v=0;v<3;++v){t.iA[v]=3*u+v; t.jB[v]=3*x+v; t.sg[v]=1;}} break;
    case 13: for (int w=0;w<9;++w){t.iA[w]=w; t.jB[w]=w; t.sg[w]=1;} break;
    case 14: {int p=mo,u1=(p+1)%3,u2=(p+2)%3;
              for(int v=0;v<3;++v){
                t.iA[2*v]  =3*u1+v; t.jB[2*v]  =3*u2+v; t.sg[2*v]  = 1;
                t.iA[2*v+1]=3*u2+v; t.jB[2*v+1]=3*u1+v; t.sg[2*v+1]=-1;}} break;
  }
  return t;
}

DEVINL u16 f2bf(float f) {            // RNE float->bf16
  uint32 u = __float_as_uint(f);
  u += 0x7fffu + ((u >> 16) & 1u);
  return (u16)(u >> 16);
}
DEVINL float bf2f(u16 h) { return __uint_as_float(((uint32)h) << 16); }

DEVINL void unpack8(uint4 r, fx2 out[4]) {   // sign applied on A scalar instead
  uint32 c[4] = {r.x, r.y, r.z, r.w};
#pragma unroll
  for (int q = 0; q < 4; ++q) {
    out[q].x = __uint_as_float(c[q] << 16);
    out[q].y = __uint_as_float(c[q] & 0xffff0000u);
  }
}

DEVINL bf16x8 packA(const fx2 p[4]) { // pack 8 f32 -> 8 bf16 (truncate)
  U4H r;
  r.u.x = __builtin_amdgcn_perm(__float_as_uint(p[0].y), __float_as_uint(p[0].x), 0x07060302u);
  r.u.y = __builtin_amdgcn_perm(__float_as_uint(p[1].y), __float_as_uint(p[1].x), 0x07060302u);
  r.u.z = __builtin_amdgcn_perm(__float_as_uint(p[2].y), __float_as_uint(p[2].x), 0x07060302u);
  r.u.w = __builtin_amdgcn_perm(__float_as_uint(p[3].y), __float_as_uint(p[3].x), 0x07060302u);
  return r.h;
}

DEVINL f32x16 mfma32(bf16x8 a, uint4 w, f32x16 c) {
  U4H x; x.u = w;
  return __builtin_amdgcn_mfma_f32_32x32x16_bf16(a, x.h, c, 0, 0, 0);
}

// x1l row stride: 834 u16 = 417 dwords == 1 (mod 32) -> the 32-row fixed-column
// read pattern hits all 32 banks (conflict-free).
#define X1STRIDE 834

// ---------------- per-combo worker (R9 shape: fat wave) ---------------------
// Team-local wave wvt in [0,8): bh = wvt&1 (16-wide b half), a0 = (wvt>>1)*8
// (8 'a' channels), wf[8] resident. This is exactly R9's per-wave instruction
// stream (88 VGPR, deep load batching) -- R10's thin wf[4]/a0*4 layout
// collapsed to 64 VGPR and serialized on memory latency (VALUBusy 29.6->21.9
// DESPITE 2x waves). Overhead (b2 loads/unpacks) amortized over 8 MFMAs.
template<int PATH, int MO>
DEVINL void run_combo(int s1, int s2, int n0,
                      const u16* __restrict__ x2t, const u16* x1l,
                      const uint4* __restrict__ wgl,
                      f32x16& acc, int lane, int wvt)
{
  constexpr int L1v = PL1c[PATH];
  constexpr int L2v = PL2c[PATH];
  constexpr int T   = PTc[PATH];
  constexpr int P1v = PW3c[L1v];
  constexpr int NCH = (T + 2) / 3;
  const int bh   = wvt & 1;
  const int a0   = (wvt >> 1) * 8;
  const int nloc = lane & 31;
  const int oct  = lane >> 5;
  const u16* bb = x2t + (size_t)(n0 + nloc) * 832 + s2 * 416 + LOFFc[L2v]
                + bh * 16 + oct * 8;
  const u16* ab = x1l + nloc * X1STRIDE + s1 * 416 + LOFFc[L1v];
  const uint4* wbase = wgl + ((a0 * 2 + bh) << 6) + lane;
  uint4 wf[8];                           // resident for the whole combo
#pragma unroll
  for (int ia = 0; ia < 8; ++ia)
    wf[ia] = wbase[ia * 128];            // global_load_dwordx4, L2 hit
  const Terms tm = make_terms(PATH, MO); // PATH, MO compile-time -> folded
#pragma unroll
  for (int tc = 0; tc < NCH; ++tc) {
    const int tlo = tc * 3;
    const int tn  = (T - tlo < 3) ? (T - tlo) : 3;
    fx2 b2[3][4];
#pragma unroll
    for (int u = 0; u < 3; ++u)
      if (u < tn) {
        uint4 rv = *(const uint4*)(bb + tm.jB[tlo + u] * 32);
        unpack8(rv, b2[u]);
      }
#pragma unroll
    for (int ia = 0; ia < 8; ++ia) {
      fx2 p[4];
#pragma unroll
      for (int u = 0; u < 3; ++u) {
        if (u < tn) {
          float av = bf2f(ab[(a0 + ia) * P1v + tm.iA[tlo + u]]);
          if (tm.sg[tlo + u] < 0) av = -av;
          fx2 a2; a2.x = av; a2.y = av;
          if (u == 0) {
#pragma unroll
            for (int q = 0; q < 4; ++q) p[q] = a2 * b2[0][q];
          } else {
#pragma unroll
            for (int q = 0; q < 4; ++q)
              p[q] = __builtin_elementwise_fma(a2, b2[u][q], p[q]);
          }
        }
      }
      acc = mfma32(packA(p), wf[ia], acc);
    }
  }
}

// accumulate one chunk (single t = MOB) over ALL combos of group G.
// NO barriers inside (safe under team divergence).
template<int G, int MOB>
DEVINL void accum_chunk(int n0, const u16* __restrict__ x2t, const u16* x1l,
                        const uint4* __restrict__ Wb,
                        f32x16& acc, int lane, int wvt)
{
  constexpr int lout = G >> 1;
#pragma unroll 1
  for (int ci = 0; ci < GCNT[G]; ++ci) {
    const int path = g_combo[G][ci][0];
    const int s1   = g_combo[G][ci][1];
    const int s2   = g_combo[G][ci][2];
    const int pc   = path * 4 + s1 * 2 + s2;
    const uint4* wgl = Wb + ((size_t)pc << 12);
#define RCASE(P) case P: if constexpr (PLOc[P] == lout) \
      run_combo<P, MOB>(s1, s2, n0, x2t, x1l, wgl, acc, lane, wvt); break;
    switch (path) {
      RCASE(0) RCASE(1) RCASE(2) RCASE(3) RCASE(4) RCASE(5) RCASE(6) RCASE(7)
      RCASE(8) RCASE(9) RCASE(10) RCASE(11) RCASE(12) RCASE(13) RCASE(14)
    }
#undef RCASE
    __builtin_amdgcn_sched_barrier(0);   // no cross-combo code motion
  }
}

// ---------------- one lockstep round: team0 does <GA,MOA>, team1 <GB,MOB_> --
// R11/R12: 16 waves = 2 teams x 8. Divergence is confined to the barrier-free
// accumulation; the flush (with its 2 __syncthreads) is a single convergent
// call site. Round pairing (G0|G1),(G2|G3)x3,(G5|G4)x9 gives IDENTICAL
// per-round MFMA counts (80, 112x3, 96x9) -> teams stay in lockstep.
// red[2][1024]: per-team accumulator; 8-wave atomic contention (same as R9).
// Store: coalesced full-line writes into column-major scratch sc[col][n]
// (128B contiguous per 32 lanes -> no partial-line RMW). k_tr -> out.
// red swizzle (col<<5)+((row+col)&31): conflict-free for atomics and reads.
template<int GA, int MOA, int GB, int MOB_>
DEVINL void process_round(int n0, const u16* __restrict__ x2t, const u16* x1l,
                          const uint4* __restrict__ Wb, float* red,
                          float* __restrict__ out, float* __restrict__ sc,
                          int use_sc, int tid, int lane, int wvt, int tm)
{
  f32x16 acc;
#pragma unroll
  for (int e = 0; e < 16; ++e) acc[e] = 0.f;
  if (tm == 0) accum_chunk<GA, MOA>(n0, x2t, x1l, Wb, acc, lane, wvt);
  else         accum_chunk<GB, MOB_>(n0, x2t, x1l, Wb, acc, lane, wvt);

  const int col = lane & 31, oct = lane >> 5;
  float* redt = red + (tm << 10);
  __syncthreads();                       // red zeroed & prior readers done
#pragma unroll
  for (int r = 0; r < 16; ++r) {
    int row = (r & 3) + 8 * (r >> 2) + 4 * oct;   // m74/m101 C/D layout
    atomicAdd(&redt[(col << 5) + ((row + col) & 31)], acc[r]);
  }
  __syncthreads();                       // all atomics done
  constexpr int obaseA = (GA & 1) * 416 + LOFFc[GA >> 1];
  constexpr int obaseB = (GB & 1) * 416 + LOFFc[GB >> 1];
  const int obase = tm ? obaseB : obaseA;
  const int NTF   = tm ? GNT[GB] : GNT[GA];
  const int MOx   = tm ? MOB_ : MOA;
  const int tidt  = tid & 511;
  for (int o = tidt; o < 1024; o += 512) {
    int row = o & 31;                    // row fastest -> coalesced sc write
    int Z   = o >> 5;
    int idx = (tm << 10) + (Z << 5) + ((row + Z) & 31);
    float v = red[idx];
    red[idx] = 0.f;                      // restore invariant for next round
    int colx = obase + Z * NTF + MOx;
    if (use_sc) sc[(size_t)colx * 8192 + n0 + row] = v;
    else        out[(size_t)(n0 + row) * 832 + colx] = v;
  }
}

// ---------------- main kernel ----------------------------------------------
// R11/R12: ONE 1024-thread workgroup per slab (grid 256): 16 waves
// co-resident by construction (R10 proved 49% occupancy) but with R9's fat
// per-wave shape restored via the 2-team split. __launch_bounds__(1024,4):
// 4 waves/EU is exactly a 16-wave workgroup -> VGPR cap 128 (R9 needed 88).
// LDS: x1l 53,376 + red 8,192 = 61,568 B.
__global__ __launch_bounds__(1024, 4)
void k_main(const float* __restrict__ x1, const u16* __restrict__ x2t,
            const uint4* __restrict__ Wb, float* __restrict__ out,
            float* __restrict__ sc, int use_sc)
{
  __shared__ u16   x1l[32 * X1STRIDE]; // 53,376 B (stride 834: conflict-free)
  __shared__ float red[2048];          // 8,192 B: per-team accumulators
  const int tid  = threadIdx.x;
  const int lane = tid & 63, wv = tid >> 6;
  const int wvt  = wv & 7, tm = wv >> 3;
  const int n0   = blockIdx.x * 32;

  { // stage x1 rows -> bf16 LDS (once): 32 threads per row, 26 cols each
    int rr = tid >> 5, c0 = tid & 31;
    const float* src = x1 + (size_t)(n0 + rr) * 832;
#pragma unroll 2
    for (int jj = 0; jj < 26; ++jj) {
      int colx = c0 + jj * 32;
      x1l[rr * X1STRIDE + colx] = f2bf(src[colx]);
    }
  }
  for (int o = tid; o < 2048; o += 1024) red[o] = 0.f;  // flush invariant
  __syncthreads();                       // x1l staged + red zeroed

  process_round<0, 0, 1, 0>(n0, x2t, x1l, Wb, red, out, sc, use_sc, tid, lane, wvt, tm);
  process_round<2, 0, 3, 0>(n0, x2t, x1l, Wb, red, out, sc, use_sc, tid, lane, wvt, tm);
  process_round<2, 1, 3, 1>(n0, x2t, x1l, Wb, red, out, sc, use_sc, tid, lane, wvt, tm);
  process_round<2, 2, 3, 2>(n0, x2t, x1l, Wb, red, out, sc, use_sc, tid, lane, wvt, tm);
  process_round<5, 0, 4, 0>(n0, x2t, x1l, Wb, red, out, sc, use_sc, tid, lane, wvt, tm);
  process_round<5, 1, 4, 1>(n0, x2t, x1l, Wb, red, out, sc, use_sc, tid, lane, wvt, tm);
  process_round<5, 2, 4, 2>(n0, x2t, x1l, Wb, red, out, sc, use_sc, tid, lane, wvt, tm);
  process_round<5, 3, 4, 3>(n0, x2t, x1l, Wb, red, out, sc, use_sc, tid, lane, wvt, tm);
  process_round<5, 4, 4, 4>(n0, x2t, x1l, Wb, red, out, sc, use_sc, tid, lane, wvt, tm);
  process_round<5, 5, 4, 5>(n0, x2t, x1l, Wb, red, out, sc, use_sc, tid, lane, wvt, tm);
  process_round<5, 6, 4, 6>(n0, x2t, x1l, Wb, red, out, sc, use_sc, tid, lane, wvt, tm);
  process_round<5, 7, 4, 7>(n0, x2t, x1l, Wb, red, out, sc, use_sc, tid, lane, wvt, tm);
  process_round<5, 8, 4, 8>(n0, x2t, x1l, Wb, red, out, sc, use_sc, tid, lane, wvt, tm);
}

// ---------------- transpose kernel: sc[col][n] -> out[n][col] ---------------
// 32 cols x 64 rows per block; both global phases fully coalesced/full-line.
__global__ __launch_bounds__(256)
void k_tr(const float* __restrict__ sc, float* __restrict__ out)
{
  __shared__ float tile[32][65];
  const int tid = threadIdx.x;
  const int cb  = blockIdx.x % 26;
  const int nbk = blockIdx.x / 26;
  if (cb >= 26 || nbk >= 128) return;    // defensive (grid == 26*128 exactly)
  const int c0  = cb * 32;
  const int nb  = nbk * 64;
#pragma unroll
  for (int it = 0; it < 8; ++it) {
    int idx = it * 256 + tid;
    int c = idx >> 6, n = idx & 63;      // n fastest -> coalesced read
    tile[c][n] = sc[(size_t)(c0 + c) * 8192 + nb + n];
  }
  __syncthreads();
#pragma unroll
  for (int it = 0; it < 8; ++it) {
    int idx = it * 256 + tid;
    int c = idx & 31, n = idx >> 5;      // c fastest -> coalesced write
    out[(size_t)(nb + n) * 832 + c0 + c] = tile[c][n];
  }
}

// ---------------- pre-kernels ----------------------------------------------
// W -> bf16, swizzled into exact B-fragment lane order:
//   Wb[pc][a][bh][l][j] = bf16( w[pc*32768 + Z*1024 + a*32 + b] ),
//   Z = l&31, b = bh*16 + ((l>>5)&1)*8 + j
__global__ void k_convw(const float* __restrict__ w, u16* __restrict__ Wb) {
  int o  = blockIdx.x * 1024 + threadIdx.x;      // 1,966,080 total
  int j  = o & 7;
  int l  = (o >> 3) & 63;
  int bh = (o >> 9) & 1;
  int a  = (o >> 10) & 31;
  int pc = o >> 15;
  int Z  = l & 31;
  int b  = bh * 16 + ((l >> 5) & 1) * 8 + j;
  float f = w[((size_t)pc << 15) + (size_t)Z * 1024 + a * 32 + b];
  Wb[o] = f2bf(f);
}

// x2 -> bf16, transposed within each (s,L) block to [j][b] so 8 consecutive
// b-channels are one 16B load: x2t[n*832 + s*416 + Loff + j*32 + b]
__global__ void k_convx2(const float* __restrict__ x2, u16* __restrict__ x2t) {
  int o = blockIdx.x * 1024 + threadIdx.x;       // 6,815,744 total
  int n = o / 832; int r = o - n * 832;
  int s = (r >= 416); int r2 = r - s * 416;
  int L = (r2 >= 32) + (r2 >= 128);
  int off = (L == 0) ? 0 : ((L == 1) ? 32 : 128);
  int c = r2 - off;
  int j = c >> 5, b = c & 31;
  int p3 = (L == 0) ? 1 : ((L == 1) ? 3 : 9);
  float f = x2[(size_t)n * 832 + s * 416 + off + b * p3 + j];
  x2t[o] = f2bf(f);
}

// ---------------- launch ----------------------------------------------------
extern "C" void kernel_launch(void* const* d_in, const int* in_sizes, int n_in,
                              void* d_out, int out_size, void* d_ws, size_t ws_size,
                              hipStream_t stream) {
  const float* x1 = (const float*)d_in[0];
  const float* x2 = (const float*)d_in[1];
  const float* w  = (const float*)d_in[2];
  float* out = (float*)d_out;
  // ws layout: [0,4MB) swizzled bf16 W ; [4MB,~17.6MB) bf16 x2t ;
  //            [20MB, 20MB+27.3MB) f32 scratch sc[832][8192]
  u16*   Wb  = (u16*)d_ws;
  u16*   x2t = (u16*)((char*)d_ws + (4u << 20));
  float* sc  = (float*)((char*)d_ws + (20u << 20));
  const size_t sc_need = (20u << 20) + (size_t)832 * 8192 * 4;
  const int use_sc = (ws_size >= sc_need) ? 1 : 0;
  (void)in_sizes; (void)n_in; (void)out_size;

  k_convw <<<1920, 1024, 0, stream>>>(w, Wb);    // 1920*1024 = 1,966,080
  k_convx2<<<6656, 1024, 0, stream>>>(x2, x2t);  // 6656*1024 = 6,815,744
  k_main  <<<256, 1024, 0, stream>>>(x1, x2t, (const uint4*)Wb, out, sc, use_sc);
  if (use_sc) k_tr<<<26 * 128, 256, 0, stream>>>(sc, out);
}

// Round 8
// 723.691 us; speedup vs baseline: 1.5000x; 1.0804x over previous
//
#include <hip/hip_runtime.h>

#define DEVINL __device__ __forceinline__

typedef unsigned int  uint32;
typedef unsigned short u16;

typedef short bf16x8  __attribute__((ext_vector_type(8)));
typedef float f32x16  __attribute__((ext_vector_type(16)));
typedef float fx2     __attribute__((ext_vector_type(2)));

union U4H { uint4 u; bf16x8 h; };

// ---------------- path tables (15 paths, enumeration order of reference) ----
// idx: 0:(0,0,0,0,F) 1:(0,1,1,0,F) 2:(0,2,2,0,F) 3:(1,0,1,0,F) 4:(1,1,2,0,F)
//      5:(1,1,0,1,F) 6:(1,1,1,0,T) 7:(1,2,1,1,F) 8:(1,2,2,0,T) 9:(2,0,2,0,F)
//     10:(2,1,1,1,F) 11:(2,1,2,0,T) 12:(2,2,2,1,F) 13:(2,2,0,2,F) 14:(2,2,1,1,T)
constexpr int PL1c[15] = {0,0,0,1,1,1,1,1,1,2,2,2,2,2,2};
constexpr int PL2c[15] = {0,1,2,0,1,1,1,2,2,0,1,1,2,2,2};
constexpr int PLOc[15] = {0,1,2,1,2,0,1,1,2,2,1,2,2,0,1};
constexpr int PTc [15] = {1,1,1,1,1,3,2,3,2,1,3,2,3,9,6};
constexpr int PW3c[3]  = {1,3,9};
constexpr int LOFFc[3] = {0,32,128};

// groups g = (s_out = g&1, Lout = g>>1); combos (path, s1, s2)
constexpr int GCNT[6] = {6,6,12,12,12,12};
constexpr int GNT [6] = {1,1,3,3,9,9};
__device__ const int g_combo[6][12][3] = {
  {{0,0,0},{0,1,1},{5,0,0},{5,1,1},{13,0,0},{13,1,1},
   {0,0,0},{0,0,0},{0,0,0},{0,0,0},{0,0,0},{0,0,0}},
  {{0,0,1},{0,1,0},{5,0,1},{5,1,0},{13,0,1},{13,1,0},
   {0,0,0},{0,0,0},{0,0,0},{0,0,0},{0,0,0},{0,0,0}},
  {{1,0,0},{1,1,1},{3,0,0},{3,1,1},{7,0,0},{7,1,1},{10,0,0},{10,1,1},
   {6,0,1},{6,1,0},{14,0,1},{14,1,0}},
  {{1,0,1},{1,1,0},{3,0,1},{3,1,0},{7,0,1},{7,1,0},{10,0,1},{10,1,0},
   {6,0,0},{6,1,1},{14,0,0},{14,1,1}},
  {{2,0,0},{2,1,1},{4,0,0},{4,1,1},{9,0,0},{9,1,1},{12,0,0},{12,1,1},
   {8,0,1},{8,1,0},{11,0,1},{11,1,0}},
  {{2,0,1},{2,1,0},{4,0,1},{4,1,0},{9,0,1},{9,1,0},{12,0,1},{12,1,0},
   {8,0,0},{8,1,1},{11,0,0},{11,1,1}},
};

struct Terms { int iA[9]; int jB[9]; int sg[9]; };

DEVINL Terms make_terms(int path, int mo) {
  Terms t{};
  switch (path) {
    case 0:  t.iA[0]=0;  t.jB[0]=0;  t.sg[0]=1; break;
    case 1:  t.iA[0]=0;  t.jB[0]=mo; t.sg[0]=1; break;
    case 2:  t.iA[0]=0;  t.jB[0]=mo; t.sg[0]=1; break;
    case 3:  t.iA[0]=mo; t.jB[0]=0;  t.sg[0]=1; break;
    case 4:  t.iA[0]=mo/3; t.jB[0]=mo%3; t.sg[0]=1; break;
    case 5:  for (int v=0;v<3;++v){t.iA[v]=v; t.jB[v]=v; t.sg[v]=1;} break;
    case 6:  {int p=mo,u1=(p+1)%3,u2=(p+2)%3;
              t.iA[0]=u1; t.jB[0]=u2; t.sg[0]= 1;
              t.iA[1]=u2; t.jB[1]=u1; t.sg[1]=-1;} break;
    case 7:  {int x=mo; for(int u=0;u<3;++u){t.iA[u]=u; t.jB[u]=3*x+u; t.sg[u]=1;}} break;
    case 8:  {int x=mo/3,p=mo%3,u1=(p+1)%3,u2=(p+2)%3;
              t.iA[0]=u1; t.jB[0]=3*x+u2; t.sg[0]= 1;
              t.iA[1]=u2; t.jB[1]=3*x+u1; t.sg[1]=-1;} break;
    case 9:  t.iA[0]=mo; t.jB[0]=0; t.sg[0]=1; break;
    case 10: {int u=mo; for(int v=0;v<3;++v){t.iA[v]=3*u+v; t.jB[v]=v; t.sg[v]=1;}} break;
    case 11: {int u=mo/3,p=mo%3,v1=(p+1)%3,v2=(p+2)%3;
              t.iA[0]=3*u+v1; t.jB[0]=v2; t.sg[0]= 1;
              t.iA[1]=3*u+v2; t.jB[1]=v1; t.sg[1]=-1;} break;
    case 12: {int u=mo/3,x=mo%3; for(int v=0;v<3;++v){t.iA[v]=3*u+v; t.jB[v]=3*x+v; t.sg[v]=1;}} break;
    case 13: for (int w=0;w<9;++w){t.iA[w]=w; t.jB[w]=w; t.sg[w]=1;} break;
    case 14: {int p=mo,u1=(p+1)%3,u2=(p+2)%3;
              for(int v=0;v<3;++v){
                t.iA[2*v]  =3*u1+v; t.jB[2*v]  =3*u2+v; t.sg[2*v]  = 1;
                t.iA[2*v+1]=3*u2+v; t.jB[2*v+1]=3*u1+v; t.sg[2*v+1]=-1;}} break;
  }
  return t;
}

DEVINL u16 f2bf(float f) {            // RNE float->bf16
  uint32 u = __float_as_uint(f);
  u += 0x7fffu + ((u >> 16) & 1u);
  return (u16)(u >> 16);
}

DEVINL void unpack8(uint4 r, fx2 out[4]) {   // sign applied on A scalar instead
  uint32 c[4] = {r.x, r.y, r.z, r.w};
#pragma unroll
  for (int q = 0; q < 4; ++q) {
    out[q].x = __uint_as_float(c[q] << 16);
    out[q].y = __uint_as_float(c[q] & 0xffff0000u);
  }
}

DEVINL bf16x8 packA(const fx2 p[4]) { // pack 8 f32 -> 8 bf16 (truncate)
  U4H r;
  r.u.x = __builtin_amdgcn_perm(__float_as_uint(p[0].y), __float_as_uint(p[0].x), 0x07060302u);
  r.u.y = __builtin_amdgcn_perm(__float_as_uint(p[1].y), __float_as_uint(p[1].x), 0x07060302u);
  r.u.z = __builtin_amdgcn_perm(__float_as_uint(p[2].y), __float_as_uint(p[2].x), 0x07060302u);
  r.u.w = __builtin_amdgcn_perm(__float_as_uint(p[3].y), __float_as_uint(p[3].x), 0x07060302u);
  return r.h;
}

DEVINL f32x16 mfma32(bf16x8 a, uint4 w, f32x16 c) {
  U4H x; x.u = w;
  return __builtin_amdgcn_mfma_f32_32x32x16_bf16(a, x.h, c, 0, 0, 0);
}

// R13: x1l row stride 836 u16 = 1672 B: 8B-aligned rows (ds_read_b64-legal),
// 418 dwords == 2 (mod 32) -> 32-row column reads are 2-way bank-aliased,
// which is free (m136). Both octs read the same address -> broadcast.
#define X1STRIDE 836

// ---------------- per-combo worker (fat wave + vector A-reads) --------------
// Team-local wave wvt in [0,8): bh = wvt&1 (16-wide b half), a0 = (wvt>>1)*8
// (8 'a' channels), wf[8] resident.
// R13: x1l is stored [i][a]-transposed per (s,L) block, so the 8 a-channel
// A-values for one term are 16 contiguous bytes -> 2x ds_read_b64 per term
// (was 8x ds_read_u16). Extraction is 1 VALU shift/mask per value.
template<int PATH, int MO>
DEVINL void run_combo(int s1, int s2, int n0,
                      const u16* __restrict__ x2t, const u16* x1l,
                      const uint4* __restrict__ wgl,
                      f32x16& acc, int lane, int wvt)
{
  constexpr int L1v = PL1c[PATH];
  constexpr int L2v = PL2c[PATH];
  constexpr int T   = PTc[PATH];
  constexpr int NCH = (T + 2) / 3;
  const int bh   = wvt & 1;
  const int a0   = (wvt >> 1) * 8;
  const int nloc = lane & 31;
  const int oct  = lane >> 5;
  const u16* bb = x2t + (size_t)(n0 + nloc) * 832 + s2 * 416 + LOFFc[L2v]
                + bh * 16 + oct * 8;
  const u16* ab = x1l + nloc * X1STRIDE + s1 * 416 + LOFFc[L1v] + a0;
  const uint4* wbase = wgl + ((a0 * 2 + bh) << 6) + lane;
  uint4 wf[8];                           // resident for the whole combo
#pragma unroll
  for (int ia = 0; ia < 8; ++ia)
    wf[ia] = wbase[ia * 128];            // global_load_dwordx4, L2 hit
  const Terms tm = make_terms(PATH, MO); // PATH, MO compile-time -> folded
#pragma unroll
  for (int tc = 0; tc < NCH; ++tc) {
    const int tlo = tc * 3;
    const int tn  = (T - tlo < 3) ? (T - tlo) : 3;
    fx2 b2[3][4];
    uint2 alo[3], ahi[3];
#pragma unroll
    for (int u = 0; u < 3; ++u)
      if (u < tn) {
        uint4 rv = *(const uint4*)(bb + tm.jB[tlo + u] * 32);
        unpack8(rv, b2[u]);
        const u16* ap = ab + tm.iA[tlo + u] * 32;   // [i][a]: i-row, 8 a's
        alo[u] = *(const uint2*)(ap);               // ds_read_b64
        ahi[u] = *(const uint2*)(ap + 4);           // ds_read_b64
      }
#pragma unroll
    for (int ia = 0; ia < 8; ++ia) {
      fx2 p[4];
#pragma unroll
      for (int u = 0; u < 3; ++u) {
        if (u < tn) {
          uint32 wrd = (ia < 2) ? alo[u].x : (ia < 4) ? alo[u].y
                     : (ia < 6) ? ahi[u].x : ahi[u].y;  // compile-time select
          float av = (ia & 1) ? __uint_as_float(wrd & 0xffff0000u)
                              : __uint_as_float(wrd << 16);
          if (tm.sg[tlo + u] < 0) av = -av;
          fx2 a2; a2.x = av; a2.y = av;
          if (u == 0) {
#pragma unroll
            for (int q = 0; q < 4; ++q) p[q] = a2 * b2[0][q];
          } else {
#pragma unroll
            for (int q = 0; q < 4; ++q)
              p[q] = __builtin_elementwise_fma(a2, b2[u][q], p[q]);
          }
        }
      }
      acc = mfma32(packA(p), wf[ia], acc);
    }
  }
}

// accumulate one chunk (single t = MOB) over ALL combos of group G.
// NO barriers inside (safe under team divergence).
template<int G, int MOB>
DEVINL void accum_chunk(int n0, const u16* __restrict__ x2t, const u16* x1l,
                        const uint4* __restrict__ Wb,
                        f32x16& acc, int lane, int wvt)
{
  constexpr int lout = G >> 1;
#pragma unroll 1
  for (int ci = 0; ci < GCNT[G]; ++ci) {
    const int path = g_combo[G][ci][0];
    const int s1   = g_combo[G][ci][1];
    const int s2   = g_combo[G][ci][2];
    const int pc   = path * 4 + s1 * 2 + s2;
    const uint4* wgl = Wb + ((size_t)pc << 12);
#define RCASE(P) case P: if constexpr (PLOc[P] == lout) \
      run_combo<P, MOB>(s1, s2, n0, x2t, x1l, wgl, acc, lane, wvt); break;
    switch (path) {
      RCASE(0) RCASE(1) RCASE(2) RCASE(3) RCASE(4) RCASE(5) RCASE(6) RCASE(7)
      RCASE(8) RCASE(9) RCASE(10) RCASE(11) RCASE(12) RCASE(13) RCASE(14)
    }
#undef RCASE
    __builtin_amdgcn_sched_barrier(0);   // no cross-combo code motion
  }
}

// ---------------- one lockstep round: team0 does <GA,MOA>, team1 <GB,MOB_> --
// 16 waves = 2 teams x 8. Divergence is confined to the barrier-free
// accumulation; the flush (with its 2 __syncthreads) is a single convergent
// call site. Round pairing (G0|G1),(G2|G3)x3,(G5|G4)x9 gives IDENTICAL
// per-round MFMA counts (80, 112x3, 96x9) -> teams stay in lockstep.
// red[2][1024]: per-team accumulator; 8-wave atomic contention.
// Store: coalesced full-line writes into column-major scratch sc[col][n]
// (128B contiguous per 32 lanes -> no partial-line RMW). k_tr -> out.
// red swizzle (col<<5)+((row+col)&31): conflict-free for atomics and reads.
template<int GA, int MOA, int GB, int MOB_>
DEVINL void process_round(int n0, const u16* __restrict__ x2t, const u16* x1l,
                          const uint4* __restrict__ Wb, float* red,
                          float* __restrict__ out, float* __restrict__ sc,
                          int use_sc, int tid, int lane, int wvt, int tm)
{
  f32x16 acc;
#pragma unroll
  for (int e = 0; e < 16; ++e) acc[e] = 0.f;
  if (tm == 0) accum_chunk<GA, MOA>(n0, x2t, x1l, Wb, acc, lane, wvt);
  else         accum_chunk<GB, MOB_>(n0, x2t, x1l, Wb, acc, lane, wvt);

  const int col = lane & 31, oct = lane >> 5;
  float* redt = red + (tm << 10);
  __syncthreads();                       // red zeroed & prior readers done
#pragma unroll
  for (int r = 0; r < 16; ++r) {
    int row = (r & 3) + 8 * (r >> 2) + 4 * oct;   // m74/m101 C/D layout
    atomicAdd(&redt[(col << 5) + ((row + col) & 31)], acc[r]);
  }
  __syncthreads();                       // all atomics done
  constexpr int obaseA = (GA & 1) * 416 + LOFFc[GA >> 1];
  constexpr int obaseB = (GB & 1) * 416 + LOFFc[GB >> 1];
  const int obase = tm ? obaseB : obaseA;
  const int NTF   = tm ? GNT[GB] : GNT[GA];
  const int MOx   = tm ? MOB_ : MOA;
  const int tidt  = tid & 511;
  for (int o = tidt; o < 1024; o += 512) {
    int row = o & 31;                    // row fastest -> coalesced sc write
    int Z   = o >> 5;
    int idx = (tm << 10) + (Z << 5) + ((row + Z) & 31);
    float v = red[idx];
    red[idx] = 0.f;                      // restore invariant for next round
    int colx = obase + Z * NTF + MOx;
    if (use_sc) sc[(size_t)colx * 8192 + n0 + row] = v;
    else        out[(size_t)(n0 + row) * 832 + colx] = v;
  }
}

// ---------------- main kernel ----------------------------------------------
// R13: ONE 1024-thread workgroup per slab (grid 256), 16 waves co-resident by
// construction. amdgpu_waves_per_eu(4,4): R12 showed launch_bounds' MIN arg
// lets the backend target 8 waves/EU (it thinks 2 WGs fit the 160KB LDS pool,
// but the dispatcher never co-schedules them) -> it squeezed the fat wave
// into 64 VGPR with ~300MB of scratch spill traffic (FETCH 58->284MB).
// Pinning max=4 waves/EU restores the 128-VGPR budget for the occupancy that
// actually materializes. LDS: x1l 53,504 + red 8,192 = 61,696 B.
__global__ __launch_bounds__(1024) __attribute__((amdgpu_waves_per_eu(4, 4)))
void k_main(const float* __restrict__ x1, const u16* __restrict__ x2t,
            const uint4* __restrict__ Wb, float* __restrict__ out,
            float* __restrict__ sc, int use_sc)
{
  __shared__ u16   x1l[32 * X1STRIDE]; // 53,504 B (stride 836, see above)
  __shared__ float red[2048];          // 8,192 B: per-team accumulators
  const int tid  = threadIdx.x;
  const int lane = tid & 63, wv = tid >> 6;
  const int wvt  = wv & 7, tm = wv >> 3;
  const int n0   = blockIdx.x * 32;

  { // stage x1 rows -> bf16 LDS, [i][a]-transposed per (s,L) block:
    // dest d = s*416 + LOFF + i*32 + a  <-  src col = s*416 + LOFF + a*P+i
    int rr = tid >> 5, c0 = tid & 31;
    const float* src = x1 + (size_t)(n0 + rr) * 832;
#pragma unroll 2
    for (int jj = 0; jj < 26; ++jj) {
      int d  = c0 + jj * 32;
      int s  = (d >= 416);
      int d2 = d - s * 416;
      int L  = (d2 >= 32) + (d2 >= 128);
      int off = (L == 0) ? 0 : ((L == 1) ? 32 : 128);
      int dl = d2 - off;
      int i  = dl >> 5, a = dl & 31;
      int p3 = (L == 0) ? 1 : ((L == 1) ? 3 : 9);
      x1l[rr * X1STRIDE + d] = f2bf(src[s * 416 + off + a * p3 + i]);
    }
  }
  for (int o = tid; o < 2048; o += 1024) red[o] = 0.f;  // flush invariant
  __syncthreads();                       // x1l staged + red zeroed

  process_round<0, 0, 1, 0>(n0, x2t, x1l, Wb, red, out, sc, use_sc, tid, lane, wvt, tm);
  process_round<2, 0, 3, 0>(n0, x2t, x1l, Wb, red, out, sc, use_sc, tid, lane, wvt, tm);
  process_round<2, 1, 3, 1>(n0, x2t, x1l, Wb, red, out, sc, use_sc, tid, lane, wvt, tm);
  process_round<2, 2, 3, 2>(n0, x2t, x1l, Wb, red, out, sc, use_sc, tid, lane, wvt, tm);
  process_round<5, 0, 4, 0>(n0, x2t, x1l, Wb, red, out, sc, use_sc, tid, lane, wvt, tm);
  process_round<5, 1, 4, 1>(n0, x2t, x1l, Wb, red, out, sc, use_sc, tid, lane, wvt, tm);
  process_round<5, 2, 4, 2>(n0, x2t, x1l, Wb, red, out, sc, use_sc, tid, lane, wvt, tm);
  process_round<5, 3, 4, 3>(n0, x2t, x1l, Wb, red, out, sc, use_sc, tid, lane, wvt, tm);
  process_round<5, 4, 4, 4>(n0, x2t, x1l, Wb, red, out, sc, use_sc, tid, lane, wvt, tm);
  process_round<5, 5, 4, 5>(n0, x2t, x1l, Wb, red, out, sc, use_sc, tid, lane, wvt, tm);
  process_round<5, 6, 4, 6>(n0, x2t, x1l, Wb, red, out, sc, use_sc, tid, lane, wvt, tm);
  process_round<5, 7, 4, 7>(n0, x2t, x1l, Wb, red, out, sc, use_sc, tid, lane, wvt, tm);
  process_round<5, 8, 4, 8>(n0, x2t, x1l, Wb, red, out, sc, use_sc, tid, lane, wvt, tm);
}

// ---------------- transpose kernel: sc[col][n] -> out[n][col] ---------------
// 32 cols x 64 rows per block; both global phases fully coalesced/full-line.
__global__ __launch_bounds__(256)
void k_tr(const float* __restrict__ sc, float* __restrict__ out)
{
  __shared__ float tile[32][65];
  const int tid = threadIdx.x;
  const int cb  = blockIdx.x % 26;
  const int nbk = blockIdx.x / 26;
  if (cb >= 26 || nbk >= 128) return;    // defensive (grid == 26*128 exactly)
  const int c0  = cb * 32;
  const int nb  = nbk * 64;
#pragma unroll
  for (int it = 0; it < 8; ++it) {
    int idx = it * 256 + tid;
    int c = idx >> 6, n = idx & 63;      // n fastest -> coalesced read
    tile[c][n] = sc[(size_t)(c0 + c) * 8192 + nb + n];
  }
  __syncthreads();
#pragma unroll
  for (int it = 0; it < 8; ++it) {
    int idx = it * 256 + tid;
    int c = idx & 31, n = idx >> 5;      // c fastest -> coalesced write
    out[(size_t)(nb + n) * 832 + c0 + c] = tile[c][n];
  }
}

// ---------------- pre-kernels ----------------------------------------------
// W -> bf16, swizzled into exact B-fragment lane order:
//   Wb[pc][a][bh][l][j] = bf16( w[pc*32768 + Z*1024 + a*32 + b] ),
//   Z = l&31, b = bh*16 + ((l>>5)&1)*8 + j
__global__ void k_convw(const float* __restrict__ w, u16* __restrict__ Wb) {
  int o  = blockIdx.x * 1024 + threadIdx.x;      // 1,966,080 total
  int j  = o & 7;
  int l  = (o >> 3) & 63;
  int bh = (o >> 9) & 1;
  int a  = (o >> 10) & 31;
  int pc = o >> 15;
  int Z  = l & 31;
  int b  = bh * 16 + ((l >> 5) & 1) * 8 + j;
  float f = w[((size_t)pc << 15) + (size_t)Z * 1024 + a * 32 + b];
  Wb[o] = f2bf(f);
}

// x2 -> bf16, transposed within each (s,L) block to [j][b] so 8 consecutive
// b-channels are one 16B load: x2t[n*832 + s*416 + Loff + j*32 + b]
__global__ void k_convx2(const float* __restrict__ x2, u16* __restrict__ x2t) {
  int o = blockIdx.x * 1024 + threadIdx.x;       // 6,815,744 total
  int n = o / 832; int r = o - n * 832;
  int s = (r >= 416); int r2 = r - s * 416;
  int L = (r2 >= 32) + (r2 >= 128);
  int off = (L == 0) ? 0 : ((L == 1) ? 32 : 128);
  int c = r2 - off;
  int j = c >> 5, b = c & 31;
  int p3 = (L == 0) ? 1 : ((L == 1) ? 3 : 9);
  float f = x2[(size_t)n * 832 + s * 416 + off + b * p3 + j];
  x2t[o] = f2bf(f);
}

// ---------------- launch ----------------------------------------------------
extern "C" void kernel_launch(void* const* d_in, const int* in_sizes, int n_in,
                              void* d_out, int out_size, void* d_ws, size_t ws_size,
                              hipStream_t stream) {
  const float* x1 = (const float*)d_in[0];
  const float* x2 = (const float*)d_in[1];
  const float* w  = (const float*)d_in[2];
  float* out = (float*)d_out;
  // ws layout: [0,4MB) swizzled bf16 W ; [4MB,~17.6MB) bf16 x2t ;
  //            [20MB, 20MB+27.3MB) f32 scratch sc[832][8192]
  u16*   Wb  = (u16*)d_ws;
  u16*   x2t = (u16*)((char*)d_ws + (4u << 20));
  float* sc  = (float*)((char*)d_ws + (20u << 20));
  const size_t sc_need = (20u << 20) + (size_t)832 * 8192 * 4;
  const int use_sc = (ws_size >= sc_need) ? 1 : 0;
  (void)in_sizes; (void)n_in; (void)out_size;

  k_convw <<<1920, 1024, 0, stream>>>(w, Wb);    // 1920*1024 = 1,966,080
  k_convx2<<<6656, 1024, 0, stream>>>(x2, x2t);  // 6656*1024 = 6,815,744
  k_main  <<<256, 1024, 0, stream>>>(x1, x2t, (const uint4*)Wb, out, sc, use_sc);
  if (use_sc) k_tr<<<26 * 128, 256, 0, stream>>>(sc, out);
}